// Round 4
// baseline (345.378 us; speedup 1.0000x reference)
//
#include <hip/hip_runtime.h>
#include <hip/hip_bf16.h>

// L0 contraction: B rows x 15 fp32 features -> B rows x 3 fp32 outputs.
// out[b][s] = cg_s * sum_{j in seg s} sphc[b][j]^2, segment widths {3,5,7},
// cg values at flat indices {0,3,8} of cg_rep.
//
// Memory-bound: 240 MB in + 48 MB out = 288 MB -> ~46 us floor at 6.3 TB/s.
//
// R4: no-LDS restructure. Each thread owns 4 consecutive rows = 60 floats
// = 240 B (16B-aligned), loaded as 15 aligned dwordx4. The wave's 15-load
// loop covers a dense 15 KB footprint, so L1 captures full cache-line
// utilization despite the 240 B lane stride. Output = 12 contiguous floats
// = 3 aligned nontemporal dwordx4 stores. No barriers, no LDS round-trip —
// removes the per-block vmcnt(0)+s_barrier drain that throttled issue in
// the R1-R3 staged version. B = 4,000,000 is divisible by 4, so every
// active thread takes the full path (generic tail loop kept for safety).

constexpr int M = 15;          // features per row
constexpr int NSEG = 3;        // output segments
constexpr int RPT = 4;         // rows per thread
constexpr int BLK = 256;

typedef float f32x4 __attribute__((ext_vector_type(4)));

__global__ __launch_bounds__(BLK)
void l0_contract_direct(const float* __restrict__ sphc,
                        const float* __restrict__ cg_rep,
                        float* __restrict__ out,
                        int B) {
    const long long gid = (long long)blockIdx.x * BLK + threadIdx.x;
    const long long r0 = gid * RPT;
    if (r0 >= B) return;

    const float c1 = cg_rep[0];  // l=1 block (3 elems)
    const float c2 = cg_rep[3];  // l=2 block (5 elems)
    const float c3 = cg_rep[8];  // l=3 block (7 elems)

    if (r0 + RPT <= B) {
        // ---- fast path: 4 rows = 15 aligned f32x4 loads ----
        const f32x4* __restrict__ g4 = (const f32x4*)sphc + gid * (M * RPT / 4);
        f32x4 v[M * RPT / 4];  // 15 vec4 = 60 floats
#pragma unroll
        for (int i = 0; i < M * RPT / 4; ++i) v[i] = g4[i];
        const float* f = (const float*)v;

        f32x4 o[RPT * NSEG / 4];  // 3 vec4 = 12 floats
        float* of = (float*)o;
#pragma unroll
        for (int r = 0; r < RPT; ++r) {
            const float* x = f + r * M;
            float a = x[0] * x[0] + x[1] * x[1] + x[2] * x[2];
            float b = x[3] * x[3] + x[4] * x[4] + x[5] * x[5]
                    + x[6] * x[6] + x[7] * x[7];
            float c = x[8] * x[8] + x[9] * x[9] + x[10] * x[10]
                    + x[11] * x[11] + x[12] * x[12] + x[13] * x[13]
                    + x[14] * x[14];
            of[r * NSEG + 0] = a * c1;
            of[r * NSEG + 1] = b * c2;
            of[r * NSEG + 2] = c * c3;
        }

        f32x4* o4 = (f32x4*)out + gid * (RPT * NSEG / 4);
#pragma unroll
        for (int i = 0; i < RPT * NSEG / 4; ++i) {
            __builtin_nontemporal_store(o[i], &o4[i]);
        }
    } else {
        // ---- tail: per-row scalar (never taken when B % 4 == 0) ----
        for (long long r = r0; r < B; ++r) {
            const float* x = sphc + r * M;
            float a = x[0] * x[0] + x[1] * x[1] + x[2] * x[2];
            float b = x[3] * x[3] + x[4] * x[4] + x[5] * x[5]
                    + x[6] * x[6] + x[7] * x[7];
            float c = x[8] * x[8] + x[9] * x[9] + x[10] * x[10]
                    + x[11] * x[11] + x[12] * x[12] + x[13] * x[13]
                    + x[14] * x[14];
            float* o = out + r * NSEG;
            __builtin_nontemporal_store(a * c1, &o[0]);
            __builtin_nontemporal_store(b * c2, &o[1]);
            __builtin_nontemporal_store(c * c3, &o[2]);
        }
    }
}

extern "C" void kernel_launch(void* const* d_in, const int* in_sizes, int n_in,
                              void* d_out, int out_size, void* d_ws, size_t ws_size,
                              hipStream_t stream) {
    const float* sphc   = (const float*)d_in[0];
    const float* cg_rep = (const float*)d_in[1];
    // d_in[2] = segment_ids (int32) — segmentation is compile-time known
    float* out = (float*)d_out;

    const int B = in_sizes[0] / M;                 // 4,000,000
    const long long nThreads = ((long long)B + RPT - 1) / RPT;  // 1,000,000
    const int grid = (int)((nThreads + BLK - 1) / BLK);         // 3907

    l0_contract_direct<<<grid, BLK, 0, stream>>>(sphc, cg_rep, out, B);
}

// Round 5
// 340.262 us; speedup vs baseline: 1.0150x; 1.0150x over previous
//
#include <hip/hip_runtime.h>
#include <hip/hip_bf16.h>

// L0 contraction: B rows x 15 fp32 features -> B rows x 3 fp32 outputs.
// out[b][s] = cg_s * sum_{j in seg s} sphc[b][j]^2, segment widths {3,5,7},
// cg values at flat indices {0,3,8} of cg_rep.
//
// Memory-bound: 240 MB in + 48 MB out = 288 MB -> ~46 us floor at 6.3 TB/s.
//
// R5: persistent blocks + register-prefetch pipeline over the R1 staged
// structure (R4's no-LDS version regressed: 240 B lane stride thrashed L1).
// Grid = 2048 blocks (8/CU, exactly full occupancy at 18.4 KB LDS); each
// block grid-strides over ~7.6 tiles of 256 rows. The next tile's 4 vec4
// global loads are issued immediately after barrier A and consumed at the
// top of the next iteration, hiding load latency behind compute + store.
// Hazard analysis (2 barriers/iter, no third needed):
//   iter i: write s_in | barrier A | prefetch i+1, read s_in, write s_out
//           | barrier B | read s_out (store)
//   - s_in overwrite (iter i+1) is after barrier B(i), all s_in reads are
//     before barrier B(i)  -> safe.
//   - s_out overwrite (iter i+1) is after barrier A(i+1); all s_out reads
//     precede each thread's arrival at barrier A(i+1)  -> safe.

constexpr int M = 15;            // features per row
constexpr int NSEG = 3;          // output segments
constexpr int RPB = 256;         // rows per tile == block size
constexpr int BLK = 256;
constexpr int IN_F4 = RPB * M / 4;      // 960 vec4 per input tile
constexpr int OUT_F4 = RPB * NSEG / 4;  // 192 vec4 per output tile

typedef float f32x4 __attribute__((ext_vector_type(4)));

__global__ __launch_bounds__(BLK)
void l0_contract_pipe(const float* __restrict__ sphc,
                      const float* __restrict__ cg_rep,
                      float* __restrict__ out,
                      int nTiles) {
    __shared__ float s_in[RPB * M];     // 15360 B
    __shared__ float s_out[RPB * NSEG]; //  3072 B

    const int tid = threadIdx.x;
    const float c1 = cg_rep[0];  // l=1 block (3 elems)
    const float c2 = cg_rep[3];  // l=2 block (5 elems)
    const float c3 = cg_rep[8];  // l=3 block (7 elems)

    int tile = blockIdx.x;
    if (tile >= nTiles) return;

    // ---- prologue: load first tile into registers ----
    f32x4 v0, v1, v2, v3;
    {
        const f32x4* __restrict__ g4 = (const f32x4*)sphc + (long long)tile * IN_F4;
        v0 = g4[tid];
        v1 = g4[tid + 256];
        v2 = g4[tid + 512];
        if (tid < IN_F4 - 768) v3 = g4[tid + 768];
    }

    for (;;) {
        // ---- registers -> LDS ----
        f32x4* l4 = (f32x4*)s_in;
        l4[tid]       = v0;
        l4[tid + 256] = v1;
        l4[tid + 512] = v2;
        if (tid < IN_F4 - 768) l4[tid + 768] = v3;
        __syncthreads();  // barrier A

        // ---- issue prefetch for next tile (consumed next iteration) ----
        const int next = tile + gridDim.x;
        if (next < nTiles) {
            const f32x4* __restrict__ gn = (const f32x4*)sphc + (long long)next * IN_F4;
            v0 = gn[tid];
            v1 = gn[tid + 256];
            v2 = gn[tid + 512];
            if (tid < IN_F4 - 768) v3 = gn[tid + 768];
        }

        // ---- per-row reduction from LDS (stride 15 = odd -> <=2-way
        //      bank aliasing, free on gfx950) ----
        {
            const float* r = s_in + tid * M;
            float a = r[0] * r[0] + r[1] * r[1] + r[2] * r[2];
            float b = r[3] * r[3] + r[4] * r[4] + r[5] * r[5]
                    + r[6] * r[6] + r[7] * r[7];
            float c = r[8] * r[8] + r[9] * r[9] + r[10] * r[10]
                    + r[11] * r[11] + r[12] * r[12] + r[13] * r[13]
                    + r[14] * r[14];
            s_out[tid * NSEG + 0] = a * c1;
            s_out[tid * NSEG + 1] = b * c2;
            s_out[tid * NSEG + 2] = c * c3;
        }
        __syncthreads();  // barrier B

        // ---- LDS -> global output: coalesced nontemporal vec4 ----
        if (tid < OUT_F4) {
            const f32x4* lo4 = (const f32x4*)s_out;
            f32x4* o4 = (f32x4*)out + (long long)tile * OUT_F4;
            __builtin_nontemporal_store(lo4[tid], &o4[tid]);
        }

        if (next >= nTiles) break;
        tile = next;
    }
}

// Tail kernel (only launched if B % 256 != 0 — not the case here).
__global__ void l0_contract_tail(const float* __restrict__ sphc,
                                 const float* __restrict__ cg_rep,
                                 float* __restrict__ out,
                                 int startRow, int B) {
    const int r = startRow + blockIdx.x * blockDim.x + threadIdx.x;
    if (r >= B) return;
    const float c1 = cg_rep[0], c2 = cg_rep[3], c3 = cg_rep[8];
    const float* x = sphc + (long long)r * M;
    float a = x[0]*x[0] + x[1]*x[1] + x[2]*x[2];
    float b = x[3]*x[3] + x[4]*x[4] + x[5]*x[5] + x[6]*x[6] + x[7]*x[7];
    float c = x[8]*x[8] + x[9]*x[9] + x[10]*x[10] + x[11]*x[11]
            + x[12]*x[12] + x[13]*x[13] + x[14]*x[14];
    float* o = out + (long long)r * NSEG;
    o[0] = a * c1; o[1] = b * c2; o[2] = c * c3;
}

extern "C" void kernel_launch(void* const* d_in, const int* in_sizes, int n_in,
                              void* d_out, int out_size, void* d_ws, size_t ws_size,
                              hipStream_t stream) {
    const float* sphc   = (const float*)d_in[0];
    const float* cg_rep = (const float*)d_in[1];
    // d_in[2] = segment_ids (int32) — segmentation is compile-time known
    float* out = (float*)d_out;

    const int B = in_sizes[0] / M;   // 4,000,000
    const int nTiles = B / RPB;      // 15625 full tiles (B % 256 == 0 here)
    const int rem = B - nTiles * RPB;

    const int GRID = 2048;           // 8 blocks/CU x 256 CUs, all co-resident
    const int grid = nTiles < GRID ? nTiles : GRID;
    if (nTiles > 0) {
        l0_contract_pipe<<<grid, BLK, 0, stream>>>(sphc, cg_rep, out, nTiles);
    }
    if (rem > 0) {
        l0_contract_tail<<<(rem + 255) / 256, 256, 0, stream>>>(
            sphc, cg_rep, out, nTiles * RPB, B);
    }
}